// Round 11
// baseline (116.089 us; speedup 1.0000x reference)
//
#include <hip/hip_runtime.h>

#define DIM 512
#define NHEAD 8
#define HDIM 64
#define BATCH 4
#define SEQ 2048
#define MTOT (BATCH*SEQ)
#define SCALE 0.125f
#define LOG2E 1.4426950408889634f

typedef __bf16 bf16_t;
typedef __bf16 bf16x8 __attribute__((ext_vector_type(8)));
typedef __bf16 bf16x4 __attribute__((ext_vector_type(4)));
typedef __bf16 bf16x2 __attribute__((ext_vector_type(2)));
typedef float f32x4 __attribute__((ext_vector_type(4)));

#define ASYNC_COPY16(g, l) __builtin_amdgcn_global_load_lds( \
    (const __attribute__((address_space(1))) void*)(g),      \
    (__attribute__((address_space(3))) void*)(l), 16, 0, 0)

// ---------------- fused fp32 -> bf16 convert (x | w_qkv | w_proj) ----------------
#define NX_ELEM  (4194304)
#define NWQ_ELEM (786432)
#define NWP_ELEM (262144)
__global__ __launch_bounds__(256) void cvt_kernel(const float* __restrict__ x,
                                                  const float* __restrict__ wq,
                                                  const float* __restrict__ wp,
                                                  bf16_t* __restrict__ out) {
    int i = (blockIdx.x * 256 + threadIdx.x) * 4;
    const float* src;
    if (i < NX_ELEM)                 src = x  + i;
    else if (i < NX_ELEM + NWQ_ELEM) src = wq + (i - NX_ELEM);
    else                             src = wp + (i - NX_ELEM - NWQ_ELEM);
    float4 v = *reinterpret_cast<const float4*>(src);
    bf16x4 o;
    o[0] = (bf16_t)v.x; o[1] = (bf16_t)v.y; o[2] = (bf16_t)v.z; o[3] = (bf16_t)v.w;
    *reinterpret_cast<bf16x4*>(out + i) = o;
}

// ---------------- QKV GEMM: m97 single-buffer + V-transpose epilogue ----------------
__global__ __launch_bounds__(256) void gemm_qkv_kernel(
    const bf16_t* __restrict__ X, const bf16_t* __restrict__ W,
    const float* __restrict__ bias,
    bf16_t* __restrict__ Qo, bf16_t* __restrict__ Ko, bf16_t* __restrict__ Vto)
{
    __shared__ bf16_t smem[16384];          // As | Bs ; reused as Ls for V-transpose
    bf16_t (*As)[64] = reinterpret_cast<bf16_t (*)[64]>(smem);
    bf16_t (*Bs)[64] = reinterpret_cast<bf16_t (*)[64]>(smem + 8192);
    unsigned int* Lw = reinterpret_cast<unsigned int*>(smem);   // [128 rows][64 dwords]
    const int tid = threadIdx.x;
    const int wave = tid >> 6, lane = tid & 63;
    const int lhi = lane >> 4, llo = lane & 15;
    const int o = blockIdx.x;
    const int x = o & 7, i0 = o >> 3;
    const int m0 = (x * 8 + (i0 & 7)) * 128;
    const int n0 = (i0 >> 3) * 128;
    const int wr = (wave >> 1) * 64, wc = (wave & 1) * 64;
    f32x4 acc[4][4] = {};

    const int srow = wave * 32 + (lane >> 3);
    const int scol = (lane & 7) * 8;
    const bf16_t* gA = X + (size_t)(m0 + srow) * DIM + scol;
    const bf16_t* gB = W + (size_t)(n0 + srow) * DIM + scol;

    for (int k0 = 0; k0 < DIM; k0 += 64) {
        #pragma unroll
        for (int p = 0; p < 4; ++p) {
            ASYNC_COPY16(gA + (size_t)p * 8 * DIM + k0, &As[wave*32 + p*8][0]);
            ASYNC_COPY16(gB + (size_t)p * 8 * DIM + k0, &Bs[wave*32 + p*8][0]);
        }
        __syncthreads();
        #pragma unroll
        for (int ks = 0; ks < 2; ++ks) {
            bf16x8 af[4], bfr[4];
            #pragma unroll
            for (int i = 0; i < 4; ++i)
                af[i] = *reinterpret_cast<const bf16x8*>(&As[wr + i*16 + llo][ks*32 + lhi*8]);
            #pragma unroll
            for (int j = 0; j < 4; ++j)
                bfr[j] = *reinterpret_cast<const bf16x8*>(&Bs[wc + j*16 + llo][ks*32 + lhi*8]);
            __builtin_amdgcn_s_setprio(1);
            #pragma unroll
            for (int i = 0; i < 4; ++i)
                #pragma unroll
                for (int j = 0; j < 4; ++j)
                    acc[i][j] = __builtin_amdgcn_mfma_f32_16x16x32_bf16(af[i], bfr[j], acc[i][j], 0, 0, 0);
            __builtin_amdgcn_s_setprio(0);
        }
        __syncthreads();
    }

    const int b = m0 >> 11, ns0 = m0 & 2047;

    if (n0 < 1024) {
        #pragma unroll
        for (int j = 0; j < 4; ++j) {
            int col = n0 + wc + j*16 + llo;
            int which = col >> 9;
            int hh = (col >> 6) & 7;
            int dd = col & 63;
            float bv = bias[col];
            size_t bh = (size_t)(b * NHEAD + hh);
            #pragma unroll
            for (int i = 0; i < 4; ++i) {
                #pragma unroll
                for (int r = 0; r < 4; ++r) {
                    int ns = ns0 + wr + i*16 + lhi*4 + r;
                    float v = acc[i][j][r] + bv;
                    if (which == 0)
                        Qo[(bh * SEQ + ns) * HDIM + dd] = (bf16_t)(v * (SCALE * LOG2E));
                    else
                        Ko[(bh * SEQ + ns) * HDIM + dd] = (bf16_t)v;
                }
            }
        }
    } else {
        // V path: transpose via LDS, store V^T rows coalesced
        #pragma unroll
        for (int j = 0; j < 4; ++j) {
            int ddc = wc + j*16 + llo;
            float bv = bias[n0 + ddc];
            int xsw = (ddc & 7) * 4;
            #pragma unroll
            for (int i = 0; i < 4; ++i) {
                int dwb = (wr >> 1) + i*8 + lhi*2;
                #pragma unroll
                for (int r2 = 0; r2 < 2; ++r2) {
                    bf16x2 t;
                    t[0] = (bf16_t)(acc[i][j][2*r2]     + bv);
                    t[1] = (bf16_t)(acc[i][j][2*r2 + 1] + bv);
                    Lw[ddc * 64 + ((dwb + r2) ^ xsw)] = __builtin_bit_cast(unsigned int, t);
                }
            }
        }
        __syncthreads();
        const int hh_base = (n0 - 1024) >> 6;
        const int chunk = tid & 15;
        #pragma unroll
        for (int rd = 0; rd < 8; ++rd) {
            int ddc = rd * 16 + (tid >> 4);
            uint4 val = *reinterpret_cast<const uint4*>(
                &Lw[ddc * 64 + ((chunk * 4) ^ ((ddc & 7) * 4))]);
            int dd = ddc & 63;
            int hh = hh_base + (ddc >> 6);
            size_t bh = (size_t)(b * NHEAD + hh);
            *reinterpret_cast<uint4*>(Vto + (bh * HDIM + dd) * SEQ + ns0 + chunk * 8) = val;
        }
    }
}

// ---------------- Flash attention v10: KVBLK=128 per barrier, 64-key sub-tile pipeline ----------------
// 8 waves x 32 q (q-tile 256). 16 barrier periods; each covers two 64-key
// sub-bodies of the v9 deferred-PV pipeline. Zero-conflict XOR-swizzled LDS.
__global__ __launch_bounds__(512) void attn_kernel(
    const bf16_t* __restrict__ Q, const bf16_t* __restrict__ K,
    const bf16_t* __restrict__ Vt, bf16_t* __restrict__ O)
{
    __shared__ bf16_t Ks[2][128][64];   // [key][d], swizzled cols
    __shared__ bf16_t Vs[2][64][128];   // [d][pk],  permuted + swizzled cols
    const int tid = threadIdx.x;
    const int wave = tid >> 6, lane = tid & 63;
    const int lhi = lane >> 4, llo = lane & 15;
    const int o = blockIdx.x;
    const int w = (o & 7) * 32 + (o >> 3);
    const int qt = w & 7, bh = w >> 3;
    const bf16_t* Qb = Q + (size_t)bh * SEQ * HDIM;
    const bf16_t* Kb = K + (size_t)bh * SEQ * HDIM;
    const bf16_t* Vb = Vt + (size_t)bh * HDIM * SEQ;
    const int q0 = qt * 256 + wave * 32;

    const int ksr = tid >> 3, kg = tid & 7;
    const int kcol = (kg * 8) ^ ((ksr & 7) * 8);
    const int vd = tid >> 3, vg = tid & 7;
    const int sw = (vd & 7) * 8;
    const int pkApre = 32*(vg>>2) + 16*(vg&1) + 4*((vg>>1)&1);
    const int pkA = pkApre ^ sw, pkB = (pkApre + 8) ^ sw;   // both < 64; half1 = +64

    bf16x8 aq[2][2];
    #pragma unroll
    for (int qb = 0; qb < 2; ++qb)
        #pragma unroll
        for (int ks = 0; ks < 2; ++ks)
            aq[qb][ks] = *reinterpret_cast<const bf16x8*>(
                Qb + (size_t)(q0 + qb*16 + llo) * HDIM + ks*32 + lhi*8);

    f32x4 acc_o[2][4] = {};
    float mstat[2], lstat[2];
    lstat[0] = lstat[1] = 0.f;
    const float THR = 8.0f * LOG2E;

    uint4 kreg[2], vreg[2];
    bf16x8 apA[2][2], apB[2][2];
    bf16x8 bvA[2][4], bvB[2][4];

    // ---- prologue: stage tile 0 (128 keys) ----
    kreg[0] = *reinterpret_cast<const uint4*>(Kb + (size_t)ksr * HDIM + kg*8);
    kreg[1] = *reinterpret_cast<const uint4*>(Kb + (size_t)(ksr + 64) * HDIM + kg*8);
    vreg[0] = *reinterpret_cast<const uint4*>(Vb + (size_t)vd * SEQ + vg*8);
    vreg[1] = *reinterpret_cast<const uint4*>(Vb + (size_t)vd * SEQ + 64 + vg*8);
    *reinterpret_cast<uint4*>(&Ks[0][ksr][kcol]) = kreg[0];
    *reinterpret_cast<uint4*>(&Ks[0][ksr + 64][kcol]) = kreg[1];
    *reinterpret_cast<uint2*>(&Vs[0][vd][pkA]) = make_uint2(vreg[0].x, vreg[0].y);
    *reinterpret_cast<uint2*>(&Vs[0][vd][pkB]) = make_uint2(vreg[0].z, vreg[0].w);
    *reinterpret_cast<uint2*>(&Vs[0][vd][64 + pkA]) = make_uint2(vreg[1].x, vreg[1].y);
    *reinterpret_cast<uint2*>(&Vs[0][vd][64 + pkB]) = make_uint2(vreg[1].z, vreg[1].w);
    __syncthreads();

    // issue tile-1 loads (sub 0 is half 0)
    kreg[0] = *reinterpret_cast<const uint4*>(Kb + (size_t)(128 + ksr) * HDIM + kg*8);
    kreg[1] = *reinterpret_cast<const uint4*>(Kb + (size_t)(192 + ksr) * HDIM + kg*8);
    vreg[0] = *reinterpret_cast<const uint4*>(Vb + (size_t)vd * SEQ + 128 + vg*8);
    vreg[1] = *reinterpret_cast<const uint4*>(Vb + (size_t)vd * SEQ + 192 + vg*8);

    // ---- sub 0: full softmax init -> apA, bvA ----
    {
        f32x4 s[2][4] = {};
        __builtin_amdgcn_s_setprio(1);
        #pragma unroll
        for (int kb = 0; kb < 4; ++kb)
            #pragma unroll
            for (int ks = 0; ks < 2; ++ks) {
                bf16x8 kf = *reinterpret_cast<const bf16x8*>(
                    &Ks[0][kb*16 + llo][(ks*32 + lhi*8) ^ ((llo & 7) * 8)]);
                #pragma unroll
                for (int qb = 0; qb < 2; ++qb)
                    s[qb][kb] = __builtin_amdgcn_mfma_f32_16x16x32_bf16(kf, aq[qb][ks], s[qb][kb], 0, 0, 0);
            }
        __builtin_amdgcn_s_setprio(0);
        #pragma unroll
        for (int qb = 0; qb < 2; ++qb) {
            float mx = s[qb][0][0];
            #pragma unroll
            for (int kb = 0; kb < 4; ++kb)
                #pragma unroll
                for (int r = 0; r < 4; ++r) mx = fmaxf(mx, s[qb][kb][r]);
            mx = fmaxf(mx, __shfl_xor(mx, 16, 64));
            mx = fmaxf(mx, __shfl_xor(mx, 32, 64));
            mstat[qb] = mx;
            float rs = 0.f;
            #pragma unroll
            for (int kp = 0; kp < 2; ++kp)
                #pragma unroll
                for (int j = 0; j < 4; ++j) {
                    float p0 = __builtin_amdgcn_exp2f(s[qb][2*kp][j]     - mx);
                    float p1 = __builtin_amdgcn_exp2f(s[qb][2*kp + 1][j] - mx);
                    rs += p0 + p1;
                    apA[qb][kp][j]     = (bf16_t)p0;
                    apA[qb][kp][4 + j] = (bf16_t)p1;
                }
            lstat[qb] = rs;
        }
        #pragma unroll
        for (int kp = 0; kp < 2; ++kp)
            #pragma unroll
            for (int db = 0; db < 4; ++db)
                bvA[kp][db] = *reinterpret_cast<const bf16x8*>(
                    &Vs[0][db*16 + llo][(kp*32 + lhi*8) ^ ((llo & 7) * 8)]);
    }

    // ---- sub-body: s = 1..31; tile = s>>1, half = s&1, buf = tile&1 ----
    auto body = [&](int s, bf16x8 (&apIn)[2][2], bf16x8 (&bvIn)[2][4],
                    bf16x8 (&apOut)[2][2], bf16x8 (&bvOut)[2][4]) {
        const int tile = s >> 1, half = s & 1, cur = tile & 1, rb = half * 64;
        if (half == 0 && tile + 1 < 16) {   // issue next-tile loads
            const size_t koff = (size_t)(tile + 1) * 128;
            kreg[0] = *reinterpret_cast<const uint4*>(Kb + (koff + ksr) * HDIM + kg*8);
            kreg[1] = *reinterpret_cast<const uint4*>(Kb + (koff + 64 + ksr) * HDIM + kg*8);
            vreg[0] = *reinterpret_cast<const uint4*>(Vb + (size_t)vd * SEQ + koff + vg*8);
            vreg[1] = *reinterpret_cast<const uint4*>(Vb + (size_t)vd * SEQ + koff + 64 + vg*8);
        }
        // QK(sub s)
        f32x4 s2[2][4] = {};
        __builtin_amdgcn_s_setprio(1);
        #pragma unroll
        for (int kb = 0; kb < 4; ++kb)
            #pragma unroll
            for (int ks = 0; ks < 2; ++ks) {
                bf16x8 kf = *reinterpret_cast<const bf16x8*>(
                    &Ks[cur][rb + kb*16 + llo][(ks*32 + lhi*8) ^ ((llo & 7) * 8)]);
                #pragma unroll
                for (int qb = 0; qb < 2; ++qb)
                    s2[qb][kb] = __builtin_amdgcn_mfma_f32_16x16x32_bf16(kf, aq[qb][ks], s2[qb][kb], 0, 0, 0);
            }
        __builtin_amdgcn_s_setprio(0);

        float lmax[2];
        bool ok = true;
        #pragma unroll
        for (int qb = 0; qb < 2; ++qb) {
            float mx = s2[qb][0][0];
            #pragma unroll
            for (int kb = 0; kb < 4; ++kb)
                #pragma unroll
                for (int r = 0; r < 4; ++r) mx = fmaxf(mx, s2[qb][kb][r]);
            lmax[qb] = mx;
            ok &= (mx <= mstat[qb] + THR);
        }
        if (!__all(ok)) {   // rare: flush PV(prev) first, then rescale
            #pragma unroll
            for (int kp = 0; kp < 2; ++kp)
                #pragma unroll
                for (int db = 0; db < 4; ++db)
                    #pragma unroll
                    for (int qb = 0; qb < 2; ++qb)
                        acc_o[qb][db] = __builtin_amdgcn_mfma_f32_16x16x32_bf16(apIn[qb][kp], bvIn[kp][db], acc_o[qb][db], 0, 0, 0);
            #pragma unroll
            for (int kp = 0; kp < 2; ++kp)
                #pragma unroll
                for (int db = 0; db < 4; ++db)
                    #pragma unroll
                    for (int e = 0; e < 8; ++e) bvIn[kp][db][e] = (bf16_t)0.f;
            #pragma unroll
            for (int qb = 0; qb < 2; ++qb) {
                float mx = lmax[qb];
                mx = fmaxf(mx, __shfl_xor(mx, 16, 64));
                mx = fmaxf(mx, __shfl_xor(mx, 32, 64));
                float mold = mstat[qb];
                float mn = fmaxf(mold, mx);
                float alpha = __builtin_amdgcn_exp2f(mold - mn);
                mstat[qb] = mn;
                lstat[qb] *= alpha;
                #pragma unroll
                for (int r = 0; r < 4; ++r) {
                    float av = __shfl(alpha, (lane & 48) >> 2 | r, 64);
                    #pragma unroll
                    for (int db = 0; db < 4; ++db) acc_o[qb][db][r] *= av;
                }
            }
        }

        // interleave: exp/pack(s) -> apOut  ||  PV(s-1) from registers
        __builtin_amdgcn_s_setprio(1);
        #pragma unroll
        for (int kp = 0; kp < 2; ++kp) {
            #pragma unroll
            for (int qb = 0; qb < 2; ++qb) {
                float rs = 0.f;
                #pragma unroll
                for (int j = 0; j < 4; ++j) {
                    float p0 = __builtin_amdgcn_exp2f(s2[qb][2*kp][j]     - mstat[qb]);
                    float p1 = __builtin_amdgcn_exp2f(s2[qb][2*kp + 1][j] - mstat[qb]);
                    rs += p0 + p1;
                    apOut[qb][kp][j]     = (bf16_t)p0;
                    apOut[qb][kp][4 + j] = (bf16_t)p1;
                }
                lstat[qb] += rs;
            }
            #pragma unroll
            for (int db = 0; db < 4; ++db)
                #pragma unroll
                for (int qb = 0; qb < 2; ++qb)
                    acc_o[qb][db] = __builtin_amdgcn_mfma_f32_16x16x32_bf16(apIn[qb][kp], bvIn[kp][db], acc_o[qb][db], 0, 0, 0);
        }
        __builtin_amdgcn_s_setprio(0);

        // V(s) frags -> registers (consumed next sub)
        #pragma unroll
        for (int kp = 0; kp < 2; ++kp)
            #pragma unroll
            for (int db = 0; db < 4; ++db)
                bvOut[kp][db] = *reinterpret_cast<const bf16x8*>(
                    &Vs[cur][db*16 + llo][(rb + kp*32 + lhi*8) ^ ((llo & 7) * 8)]);

        if (half == 1 && tile + 1 < 16) {   // write next tile + single barrier
            const int nb = cur ^ 1;
            *reinterpret_cast<uint4*>(&Ks[nb][ksr][kcol]) = kreg[0];
            *reinterpret_cast<uint4*>(&Ks[nb][ksr + 64][kcol]) = kreg[1];
            *reinterpret_cast<uint2*>(&Vs[nb][vd][pkA]) = make_uint2(vreg[0].x, vreg[0].y);
            *reinterpret_cast<uint2*>(&Vs[nb][vd][pkB]) = make_uint2(vreg[0].z, vreg[0].w);
            *reinterpret_cast<uint2*>(&Vs[nb][vd][64 + pkA]) = make_uint2(vreg[1].x, vreg[1].y);
            *reinterpret_cast<uint2*>(&Vs[nb][vd][64 + pkB]) = make_uint2(vreg[1].z, vreg[1].w);
            __syncthreads();
        }
    };

    for (int sp = 1; sp + 1 < 32; sp += 2) {
        body(sp,     apA, bvA, apB, bvB);
        body(sp + 1, apB, bvB, apA, bvA);
    }
    body(31, apA, bvA, apB, bvB);

    // final PV flush (sub 31 -> B set)
    #pragma unroll
    for (int kp = 0; kp < 2; ++kp)
        #pragma unroll
        for (int db = 0; db < 4; ++db)
            #pragma unroll
            for (int qb = 0; qb < 2; ++qb)
                acc_o[qb][db] = __builtin_amdgcn_mfma_f32_16x16x32_bf16(apB[qb][kp], bvB[kp][db], acc_o[qb][db], 0, 0, 0);

    const int b = bh >> 3, h = bh & 7;
    #pragma unroll
    for (int qb = 0; qb < 2; ++qb) {
        float r = lstat[qb];
        r += __shfl_xor(r, 16, 64);
        r += __shfl_xor(r, 32, 64);
        lstat[qb] = r;
    }
    #pragma unroll
    for (int qb = 0; qb < 2; ++qb) {
        float inv = 1.0f / lstat[qb];
        #pragma unroll
        for (int r = 0; r < 4; ++r) {
            float iv = __shfl(inv, (lane & 48) >> 2 | r, 64);
            int q = q0 + qb*16 + lhi*4 + r;
            #pragma unroll
            for (int db = 0; db < 4; ++db)
                O[(size_t)(b * SEQ + q) * DIM + h*HDIM + db*16 + llo] =
                    (bf16_t)(acc_o[qb][db][r] * iv);
        }
    }
}

// ---------------- Output proj GEMM: m97, 128x64 tiles, grid 512 (2 blocks/CU) ----------------
__global__ __launch_bounds__(256) void gemm_proj_kernel(
    const bf16_t* __restrict__ X, const bf16_t* __restrict__ W,
    const float* __restrict__ bias, float* __restrict__ out)
{
    __shared__ bf16_t As[128][64];
    __shared__ bf16_t Bs[64][64];
    const int tid = threadIdx.x;
    const int wave = tid >> 6, lane = tid & 63;
    const int lhi = lane >> 4, llo = lane & 15;
    const int o = blockIdx.x;
    const int x = o & 7, i0 = o >> 3;
    const int m0 = (x * 8 + (i0 & 7)) * 128;
    const int n0 = (i0 >> 3) * 64;
    const int wr = (wave >> 1) * 64, wc = (wave & 1) * 32;
    f32x4 acc[4][2] = {};

    const int srow = wave * 32 + (lane >> 3);
    const int srowB = wave * 16 + (lane >> 3);
    const int scol = (lane & 7) * 8;
    const bf16_t* gA = X + (size_t)(m0 + srow) * DIM + scol;
    const bf16_t* gB = W + (size_t)(n0 + srowB) * DIM + scol;

    for (int k0 = 0; k0 < DIM; k0 += 64) {
        #pragma unroll
        for (int p = 0; p < 4; ++p)
            ASYNC_COPY16(gA + (size_t)p * 8 * DIM + k0, &As[wave*32 + p*8][0]);
        #pragma unroll
        for (int p = 0; p < 2; ++p)
            ASYNC_COPY16(gB + (size_t)p * 8 * DIM + k0, &Bs[wave*16 + p*8][0]);
        __syncthreads();
        #pragma unroll
        for (int ks = 0; ks < 2; ++ks) {
            bf16x8 af[4], bfr[2];
            #pragma unroll
            for (int i = 0; i < 4; ++i)
                af[i] = *reinterpret_cast<const bf16x8*>(&As[wr + i*16 + llo][ks*32 + lhi*8]);
            #pragma unroll
            for (int j = 0; j < 2; ++j)
                bfr[j] = *reinterpret_cast<const bf16x8*>(&Bs[wc + j*16 + llo][ks*32 + lhi*8]);
            __builtin_amdgcn_s_setprio(1);
            #pragma unroll
            for (int i = 0; i < 4; ++i)
                #pragma unroll
                for (int j = 0; j < 2; ++j)
                    acc[i][j] = __builtin_amdgcn_mfma_f32_16x16x32_bf16(af[i], bfr[j], acc[i][j], 0, 0, 0);
            __builtin_amdgcn_s_setprio(0);
        }
        __syncthreads();
    }

    #pragma unroll
    for (int j = 0; j < 2; ++j) {
        int col = n0 + wc + j*16 + llo;
        float bv = bias[col];
        #pragma unroll
        for (int i = 0; i < 4; ++i)
            #pragma unroll
            for (int r = 0; r < 4; ++r) {
                int m = m0 + wr + i*16 + lhi*4 + r;
                out[(size_t)m * DIM + col] = acc[i][j][r] + bv;
            }
    }
}

extern "C" void kernel_launch(void* const* d_in, const int* in_sizes, int n_in,
                              void* d_out, int out_size, void* d_ws, size_t ws_size,
                              hipStream_t stream) {
    const float* x      = (const float*)d_in[0];
    const float* w_qkv  = (const float*)d_in[1];
    const float* b_qkv  = (const float*)d_in[2];
    const float* w_proj = (const float*)d_in[3];
    const float* b_proj = (const float*)d_in[4];
    float* out = (float*)d_out;

    const size_t NX  = (size_t)MTOT * DIM;
    const size_t NWQ = (size_t)3 * DIM * DIM;
    const size_t NWP = (size_t)DIM * DIM;
    const size_t NQ  = (size_t)BATCH * NHEAD * SEQ * HDIM;

    bf16_t* Xb    = (bf16_t*)d_ws;
    bf16_t* Wqkv  = Xb + NX;
    bf16_t* Wproj = Wqkv + NWQ;
    bf16_t* Qb    = Wproj + NWP;
    bf16_t* Kb    = Qb + NQ;
    bf16_t* Vtb   = Kb + NQ;
    bf16_t* AOb   = Vtb + NQ;

    cvt_kernel<<<(int)((NX + NWQ + NWP) / 1024), 256, 0, stream>>>(x, w_qkv, w_proj, Xb);

    gemm_qkv_kernel<<<768, 256, 0, stream>>>(Xb, Wqkv, b_qkv, Qb, Kb, Vtb);

    attn_kernel<<<256, 512, 0, stream>>>(Qb, Kb, Vtb, AOb);

    gemm_proj_kernel<<<512, 256, 0, stream>>>(AOb, Wproj, b_proj, out);
}

// Round 12
// 90.159 us; speedup vs baseline: 1.2876x; 1.2876x over previous
//
#include <hip/hip_runtime.h>

#define DIM 512
#define NHEAD 8
#define HDIM 64
#define BATCH 4
#define SEQ 2048
#define MTOT (BATCH*SEQ)
#define SCALE 0.125f
#define LOG2E 1.4426950408889634f

typedef __bf16 bf16_t;
typedef __bf16 bf16x8 __attribute__((ext_vector_type(8)));
typedef __bf16 bf16x4 __attribute__((ext_vector_type(4)));
typedef __bf16 bf16x2 __attribute__((ext_vector_type(2)));
typedef float f32x4 __attribute__((ext_vector_type(4)));

#define ASYNC_COPY16(g, l) __builtin_amdgcn_global_load_lds( \
    (const __attribute__((address_space(1))) void*)(g),      \
    (__attribute__((address_space(3))) void*)(l), 16, 0, 0)

// ---------------- fused fp32 -> bf16 convert (x | w_qkv | w_proj) ----------------
#define NX_ELEM  (4194304)
#define NWQ_ELEM (786432)
#define NWP_ELEM (262144)
__global__ __launch_bounds__(256) void cvt_kernel(const float* __restrict__ x,
                                                  const float* __restrict__ wq,
                                                  const float* __restrict__ wp,
                                                  bf16_t* __restrict__ out) {
    int i = (blockIdx.x * 256 + threadIdx.x) * 4;
    const float* src;
    if (i < NX_ELEM)                 src = x  + i;
    else if (i < NX_ELEM + NWQ_ELEM) src = wq + (i - NX_ELEM);
    else                             src = wp + (i - NX_ELEM - NWQ_ELEM);
    float4 v = *reinterpret_cast<const float4*>(src);
    bf16x4 o;
    o[0] = (bf16_t)v.x; o[1] = (bf16_t)v.y; o[2] = (bf16_t)v.z; o[3] = (bf16_t)v.w;
    *reinterpret_cast<bf16x4*>(out + i) = o;
}

// ---------------- QKV GEMM: m97 single-buffer + V-transpose epilogue ----------------
__global__ __launch_bounds__(256) void gemm_qkv_kernel(
    const bf16_t* __restrict__ X, const bf16_t* __restrict__ W,
    const float* __restrict__ bias,
    bf16_t* __restrict__ Qo, bf16_t* __restrict__ Ko, bf16_t* __restrict__ Vto)
{
    __shared__ bf16_t smem[16384];          // As | Bs ; reused as Ls for V-transpose
    bf16_t (*As)[64] = reinterpret_cast<bf16_t (*)[64]>(smem);
    bf16_t (*Bs)[64] = reinterpret_cast<bf16_t (*)[64]>(smem + 8192);
    unsigned int* Lw = reinterpret_cast<unsigned int*>(smem);   // [128 rows][64 dwords]
    const int tid = threadIdx.x;
    const int wave = tid >> 6, lane = tid & 63;
    const int lhi = lane >> 4, llo = lane & 15;
    const int o = blockIdx.x;
    const int x = o & 7, i0 = o >> 3;
    const int m0 = (x * 8 + (i0 & 7)) * 128;
    const int n0 = (i0 >> 3) * 128;
    const int wr = (wave >> 1) * 64, wc = (wave & 1) * 64;
    f32x4 acc[4][4] = {};

    const int srow = wave * 32 + (lane >> 3);
    const int scol = (lane & 7) * 8;
    const bf16_t* gA = X + (size_t)(m0 + srow) * DIM + scol;
    const bf16_t* gB = W + (size_t)(n0 + srow) * DIM + scol;

    for (int k0 = 0; k0 < DIM; k0 += 64) {
        #pragma unroll
        for (int p = 0; p < 4; ++p) {
            ASYNC_COPY16(gA + (size_t)p * 8 * DIM + k0, &As[wave*32 + p*8][0]);
            ASYNC_COPY16(gB + (size_t)p * 8 * DIM + k0, &Bs[wave*32 + p*8][0]);
        }
        __syncthreads();
        #pragma unroll
        for (int ks = 0; ks < 2; ++ks) {
            bf16x8 af[4], bfr[4];
            #pragma unroll
            for (int i = 0; i < 4; ++i)
                af[i] = *reinterpret_cast<const bf16x8*>(&As[wr + i*16 + llo][ks*32 + lhi*8]);
            #pragma unroll
            for (int j = 0; j < 4; ++j)
                bfr[j] = *reinterpret_cast<const bf16x8*>(&Bs[wc + j*16 + llo][ks*32 + lhi*8]);
            __builtin_amdgcn_s_setprio(1);
            #pragma unroll
            for (int i = 0; i < 4; ++i)
                #pragma unroll
                for (int j = 0; j < 4; ++j)
                    acc[i][j] = __builtin_amdgcn_mfma_f32_16x16x32_bf16(af[i], bfr[j], acc[i][j], 0, 0, 0);
            __builtin_amdgcn_s_setprio(0);
        }
        __syncthreads();
    }

    const int b = m0 >> 11, ns0 = m0 & 2047;

    if (n0 < 1024) {
        #pragma unroll
        for (int j = 0; j < 4; ++j) {
            int col = n0 + wc + j*16 + llo;
            int which = col >> 9;
            int hh = (col >> 6) & 7;
            int dd = col & 63;
            float bv = bias[col];
            size_t bh = (size_t)(b * NHEAD + hh);
            #pragma unroll
            for (int i = 0; i < 4; ++i) {
                #pragma unroll
                for (int r = 0; r < 4; ++r) {
                    int ns = ns0 + wr + i*16 + lhi*4 + r;
                    float v = acc[i][j][r] + bv;
                    if (which == 0)
                        Qo[(bh * SEQ + ns) * HDIM + dd] = (bf16_t)(v * (SCALE * LOG2E));
                    else
                        Ko[(bh * SEQ + ns) * HDIM + dd] = (bf16_t)v;
                }
            }
        }
    } else {
        // V path: transpose via LDS, store V^T rows coalesced
        #pragma unroll
        for (int j = 0; j < 4; ++j) {
            int ddc = wc + j*16 + llo;
            float bv = bias[n0 + ddc];
            int xsw = (ddc & 7) * 4;
            #pragma unroll
            for (int i = 0; i < 4; ++i) {
                int dwb = (wr >> 1) + i*8 + lhi*2;
                #pragma unroll
                for (int r2 = 0; r2 < 2; ++r2) {
                    bf16x2 t;
                    t[0] = (bf16_t)(acc[i][j][2*r2]     + bv);
                    t[1] = (bf16_t)(acc[i][j][2*r2 + 1] + bv);
                    Lw[ddc * 64 + ((dwb + r2) ^ xsw)] = __builtin_bit_cast(unsigned int, t);
                }
            }
        }
        __syncthreads();
        const int hh_base = (n0 - 1024) >> 6;
        const int chunk = tid & 15;
        #pragma unroll
        for (int rd = 0; rd < 8; ++rd) {
            int ddc = rd * 16 + (tid >> 4);
            uint4 val = *reinterpret_cast<const uint4*>(
                &Lw[ddc * 64 + ((chunk * 4) ^ ((ddc & 7) * 4))]);
            int dd = ddc & 63;
            int hh = hh_base + (ddc >> 6);
            size_t bh = (size_t)(b * NHEAD + hh);
            *reinterpret_cast<uint4*>(Vto + (bh * HDIM + dd) * SEQ + ns0 + chunk * 8) = val;
        }
    }
}

// ---------------- Flash attention v11: v9 structure + l-via-ones-MFMA + max-tree ----------------
// 8 waves x 32 q (q-tile 256), KVBLK=64, dbuf, 1 barrier/iter, zero-conflict
// XOR-swizzled LDS, deferred-PV register pipeline. Row-sum l accumulated by
// mfma(P, ones) -> acc_l lands in acc_o row layout (no epilogue shuffles).
__global__ __launch_bounds__(512) void attn_kernel(
    const bf16_t* __restrict__ Q, const bf16_t* __restrict__ K,
    const bf16_t* __restrict__ Vt, bf16_t* __restrict__ O)
{
    __shared__ bf16_t Ks[2][64][64];
    __shared__ bf16_t Vs[2][64][64];
    const int tid = threadIdx.x;
    const int wave = tid >> 6, lane = tid & 63;
    const int lhi = lane >> 4, llo = lane & 15;
    const int o = blockIdx.x;
    const int w = (o & 7) * 32 + (o >> 3);
    const int qt = w & 7, bh = w >> 3;
    const bf16_t* Qb = Q + (size_t)bh * SEQ * HDIM;
    const bf16_t* Kb = K + (size_t)bh * SEQ * HDIM;
    const bf16_t* Vb = Vt + (size_t)bh * HDIM * SEQ;
    const int q0 = qt * 256 + wave * 32;

    const int ksr = tid >> 3, kg = tid & 7;
    const int kcol = (kg * 8) ^ ((ksr & 7) * 8);
    const int vd = tid >> 3, vg = tid & 7;
    const int pkA = (32*(vg>>2) + 8*((2*vg)&3)   + 4*((vg>>1)&1)) ^ ((vd & 7) * 8);
    const int pkB = (32*(vg>>2) + 8*((2*vg+1)&3) + 4*((vg>>1)&1)) ^ ((vd & 7) * 8);

    bf16x8 aq[2][2];
    #pragma unroll
    for (int qb = 0; qb < 2; ++qb)
        #pragma unroll
        for (int ks = 0; ks < 2; ++ks)
            aq[qb][ks] = *reinterpret_cast<const bf16x8*>(
                Qb + (size_t)(q0 + qb*16 + llo) * HDIM + ks*32 + lhi*8);

    bf16x8 ones;
    #pragma unroll
    for (int e = 0; e < 8; ++e) ones[e] = (bf16_t)1.0f;

    f32x4 acc_o[2][4] = {};
    f32x4 acc_l[2] = {};           // l in acc_o row layout: q = lhi*4+r
    float mstat[2];
    const float THR = 8.0f * LOG2E;
    const int NT = SEQ / 64;

    uint4 kreg, vreg;
    bf16x8 apA[2][2], apB[2][2];
    bf16x8 bvA[2][4], bvB[2][4];

    // max over an f32x4 (tree; v_max3-friendly)
    auto vmax4 = [](const f32x4& v) {
        return fmaxf(fmaxf(v[0], v[1]), fmaxf(v[2], v[3]));
    };

    kreg = *reinterpret_cast<const uint4*>(Kb + (size_t)ksr * HDIM + kg*8);
    vreg = *reinterpret_cast<const uint4*>(Vb + (size_t)vd * SEQ + vg*8);
    *reinterpret_cast<uint4*>(&Ks[0][ksr][kcol]) = kreg;
    *reinterpret_cast<uint2*>(&Vs[0][vd][pkA]) = make_uint2(vreg.x, vreg.y);
    *reinterpret_cast<uint2*>(&Vs[0][vd][pkB]) = make_uint2(vreg.z, vreg.w);
    __syncthreads();

    kreg = *reinterpret_cast<const uint4*>(Kb + (size_t)(64 + ksr) * HDIM + kg*8);
    vreg = *reinterpret_cast<const uint4*>(Vb + (size_t)vd * SEQ + 64 + vg*8);

    {
        f32x4 s[2][4] = {};
        __builtin_amdgcn_s_setprio(1);
        #pragma unroll
        for (int kb = 0; kb < 4; ++kb)
            #pragma unroll
            for (int ks = 0; ks < 2; ++ks) {
                bf16x8 kf = *reinterpret_cast<const bf16x8*>(
                    &Ks[0][kb*16 + llo][(ks*32 + lhi*8) ^ ((llo & 7) * 8)]);
                #pragma unroll
                for (int qb = 0; qb < 2; ++qb)
                    s[qb][kb] = __builtin_amdgcn_mfma_f32_16x16x32_bf16(kf, aq[qb][ks], s[qb][kb], 0, 0, 0);
            }
        __builtin_amdgcn_s_setprio(0);
        #pragma unroll
        for (int qb = 0; qb < 2; ++qb) {
            float mx = fmaxf(fmaxf(vmax4(s[qb][0]), vmax4(s[qb][1])),
                             fmaxf(vmax4(s[qb][2]), vmax4(s[qb][3])));
            mx = fmaxf(mx, __shfl_xor(mx, 16, 64));
            mx = fmaxf(mx, __shfl_xor(mx, 32, 64));
            mstat[qb] = mx;
            #pragma unroll
            for (int kp = 0; kp < 2; ++kp)
                #pragma unroll
                for (int j = 0; j < 4; ++j) {
                    apA[qb][kp][j]     = (bf16_t)__builtin_amdgcn_exp2f(s[qb][2*kp][j]     - mx);
                    apA[qb][kp][4 + j] = (bf16_t)__builtin_amdgcn_exp2f(s[qb][2*kp + 1][j] - mx);
                }
        }
        // l += P . 1 for tile 0
        #pragma unroll
        for (int kp = 0; kp < 2; ++kp)
            #pragma unroll
            for (int qb = 0; qb < 2; ++qb)
                acc_l[qb] = __builtin_amdgcn_mfma_f32_16x16x32_bf16(apA[qb][kp], ones, acc_l[qb], 0, 0, 0);
        #pragma unroll
        for (int kp = 0; kp < 2; ++kp)
            #pragma unroll
            for (int db = 0; db < 4; ++db)
                bvA[kp][db] = *reinterpret_cast<const bf16x8*>(
                    &Vs[0][db*16 + llo][(kp*32 + lhi*8) ^ ((llo & 7) * 8)]);
        *reinterpret_cast<uint4*>(&Ks[1][ksr][kcol]) = kreg;
        *reinterpret_cast<uint2*>(&Vs[1][vd][pkA]) = make_uint2(vreg.x, vreg.y);
        *reinterpret_cast<uint2*>(&Vs[1][vd][pkB]) = make_uint2(vreg.z, vreg.w);
        __syncthreads();
    }

    auto body = [&](int kt, bf16x8 (&apIn)[2][2], bf16x8 (&bvIn)[2][4],
                    bf16x8 (&apOut)[2][2], bf16x8 (&bvOut)[2][4]) {
        const int cur = kt & 1, nxt = cur ^ 1;
        if (kt + 1 < NT) {
            const size_t koff = (size_t)(kt + 1) * 64;
            kreg = *reinterpret_cast<const uint4*>(Kb + (koff + ksr) * HDIM + kg*8);
            vreg = *reinterpret_cast<const uint4*>(Vb + (size_t)vd * SEQ + koff + vg*8);
        }
        f32x4 s[2][4] = {};
        __builtin_amdgcn_s_setprio(1);
        #pragma unroll
        for (int kb = 0; kb < 4; ++kb)
            #pragma unroll
            for (int ks = 0; ks < 2; ++ks) {
                bf16x8 kf = *reinterpret_cast<const bf16x8*>(
                    &Ks[cur][kb*16 + llo][(ks*32 + lhi*8) ^ ((llo & 7) * 8)]);
                #pragma unroll
                for (int qb = 0; qb < 2; ++qb)
                    s[qb][kb] = __builtin_amdgcn_mfma_f32_16x16x32_bf16(kf, aq[qb][ks], s[qb][kb], 0, 0, 0);
            }
        __builtin_amdgcn_s_setprio(0);

        float lmax[2];
        bool ok = true;
        #pragma unroll
        for (int qb = 0; qb < 2; ++qb) {
            float mx = fmaxf(fmaxf(vmax4(s[qb][0]), vmax4(s[qb][1])),
                             fmaxf(vmax4(s[qb][2]), vmax4(s[qb][3])));
            lmax[qb] = mx;
            ok &= (mx <= mstat[qb] + THR);
        }
        if (!__all(ok)) {      // rare: flush PV(t-1) FIRST, then rescale
            #pragma unroll
            for (int kp = 0; kp < 2; ++kp)
                #pragma unroll
                for (int db = 0; db < 4; ++db)
                    #pragma unroll
                    for (int qb = 0; qb < 2; ++qb)
                        acc_o[qb][db] = __builtin_amdgcn_mfma_f32_16x16x32_bf16(apIn[qb][kp], bvIn[kp][db], acc_o[qb][db], 0, 0, 0);
            #pragma unroll
            for (int kp = 0; kp < 2; ++kp)
                #pragma unroll
                for (int db = 0; db < 4; ++db)
                    #pragma unroll
                    for (int e = 0; e < 8; ++e) bvIn[kp][db][e] = (bf16_t)0.f;
            #pragma unroll
            for (int qb = 0; qb < 2; ++qb) {
                float mx = lmax[qb];
                mx = fmaxf(mx, __shfl_xor(mx, 16, 64));
                mx = fmaxf(mx, __shfl_xor(mx, 32, 64));
                float mold = mstat[qb];
                float mn = fmaxf(mold, mx);
                float alpha = __builtin_amdgcn_exp2f(mold - mn);
                mstat[qb] = mn;
                #pragma unroll
                for (int r = 0; r < 4; ++r) {
                    float av = __shfl(alpha, (lane & 48) >> 2 | r, 64);
                    acc_l[qb][r] *= av;
                    #pragma unroll
                    for (int db = 0; db < 4; ++db) acc_o[qb][db][r] *= av;
                }
            }
        }

        // interleave: exp/pack(t) -> apOut || PV(t-1); l-MFMA on apOut
        __builtin_amdgcn_s_setprio(1);
        #pragma unroll
        for (int kp = 0; kp < 2; ++kp) {
            #pragma unroll
            for (int qb = 0; qb < 2; ++qb)
                #pragma unroll
                for (int j = 0; j < 4; ++j) {
                    apOut[qb][kp][j]     = (bf16_t)__builtin_amdgcn_exp2f(s[qb][2*kp][j]     - mstat[qb]);
                    apOut[qb][kp][4 + j] = (bf16_t)__builtin_amdgcn_exp2f(s[qb][2*kp + 1][j] - mstat[qb]);
                }
            #pragma unroll
            for (int db = 0; db < 4; ++db)
                #pragma unroll
                for (int qb = 0; qb < 2; ++qb)
                    acc_o[qb][db] = __builtin_amdgcn_mfma_f32_16x16x32_bf16(apIn[qb][kp], bvIn[kp][db], acc_o[qb][db], 0, 0, 0);
            #pragma unroll
            for (int qb = 0; qb < 2; ++qb)
                acc_l[qb] = __builtin_amdgcn_mfma_f32_16x16x32_bf16(apOut[qb][kp], ones, acc_l[qb], 0, 0, 0);
        }
        __builtin_amdgcn_s_setprio(0);

        #pragma unroll
        for (int kp = 0; kp < 2; ++kp)
            #pragma unroll
            for (int db = 0; db < 4; ++db)
                bvOut[kp][db] = *reinterpret_cast<const bf16x8*>(
                    &Vs[cur][db*16 + llo][(kp*32 + lhi*8) ^ ((llo & 7) * 8)]);

        if (kt + 1 < NT) {
            *reinterpret_cast<uint4*>(&Ks[nxt][ksr][kcol]) = kreg;
            *reinterpret_cast<uint2*>(&Vs[nxt][vd][pkA]) = make_uint2(vreg.x, vreg.y);
            *reinterpret_cast<uint2*>(&Vs[nxt][vd][pkB]) = make_uint2(vreg.z, vreg.w);
        }
        __syncthreads();
    };

    for (int tp = 1; tp + 1 < NT; tp += 2) {
        body(tp,     apA, bvA, apB, bvB);
        body(tp + 1, apB, bvB, apA, bvA);
    }
    body(NT - 1, apA, bvA, apB, bvB);

    // final PV flush (tile NT-1)
    #pragma unroll
    for (int kp = 0; kp < 2; ++kp)
        #pragma unroll
        for (int db = 0; db < 4; ++db)
            #pragma unroll
            for (int qb = 0; qb < 2; ++qb)
                acc_o[qb][db] = __builtin_amdgcn_mfma_f32_16x16x32_bf16(apB[qb][kp], bvB[kp][db], acc_o[qb][db], 0, 0, 0);

    // normalize: acc_l already in acc_o row layout -> no cross-lane needed
    const int b = bh >> 3, h = bh & 7;
    #pragma unroll
    for (int qb = 0; qb < 2; ++qb) {
        #pragma unroll
        for (int r = 0; r < 4; ++r) {
            float iv = 1.0f / acc_l[qb][r];
            int q = q0 + qb*16 + lhi*4 + r;
            #pragma unroll
            for (int db = 0; db < 4; ++db)
                O[(size_t)(b * SEQ + q) * DIM + h*HDIM + db*16 + llo] =
                    (bf16_t)(acc_o[qb][db][r] * iv);
        }
    }
}

// ---------------- Output proj GEMM: m97, 128x64 tiles, grid 512 (2 blocks/CU) ----------------
__global__ __launch_bounds__(256) void gemm_proj_kernel(
    const bf16_t* __restrict__ X, const bf16_t* __restrict__ W,
    const float* __restrict__ bias, float* __restrict__ out)
{
    __shared__ bf16_t As[128][64];
    __shared__ bf16_t Bs[64][64];
    const int tid = threadIdx.x;
    const int wave = tid >> 6, lane = tid & 63;
    const int lhi = lane >> 4, llo = lane & 15;
    const int o = blockIdx.x;
    const int x = o & 7, i0 = o >> 3;
    const int m0 = (x * 8 + (i0 & 7)) * 128;
    const int n0 = (i0 >> 3) * 64;
    const int wr = (wave >> 1) * 64, wc = (wave & 1) * 32;
    f32x4 acc[4][2] = {};

    const int srow = wave * 32 + (lane >> 3);
    const int srowB = wave * 16 + (lane >> 3);
    const int scol = (lane & 7) * 8;
    const bf16_t* gA = X + (size_t)(m0 + srow) * DIM + scol;
    const bf16_t* gB = W + (size_t)(n0 + srowB) * DIM + scol;

    for (int k0 = 0; k0 < DIM; k0 += 64) {
        #pragma unroll
        for (int p = 0; p < 4; ++p)
            ASYNC_COPY16(gA + (size_t)p * 8 * DIM + k0, &As[wave*32 + p*8][0]);
        #pragma unroll
        for (int p = 0; p < 2; ++p)
            ASYNC_COPY16(gB + (size_t)p * 8 * DIM + k0, &Bs[wave*16 + p*8][0]);
        __syncthreads();
        #pragma unroll
        for (int ks = 0; ks < 2; ++ks) {
            bf16x8 af[4], bfr[2];
            #pragma unroll
            for (int i = 0; i < 4; ++i)
                af[i] = *reinterpret_cast<const bf16x8*>(&As[wr + i*16 + llo][ks*32 + lhi*8]);
            #pragma unroll
            for (int j = 0; j < 2; ++j)
                bfr[j] = *reinterpret_cast<const bf16x8*>(&Bs[wc + j*16 + llo][ks*32 + lhi*8]);
            __builtin_amdgcn_s_setprio(1);
            #pragma unroll
            for (int i = 0; i < 4; ++i)
                #pragma unroll
                for (int j = 0; j < 2; ++j)
                    acc[i][j] = __builtin_amdgcn_mfma_f32_16x16x32_bf16(af[i], bfr[j], acc[i][j], 0, 0, 0);
            __builtin_amdgcn_s_setprio(0);
        }
        __syncthreads();
    }

    #pragma unroll
    for (int j = 0; j < 2; ++j) {
        int col = n0 + wc + j*16 + llo;
        float bv = bias[col];
        #pragma unroll
        for (int i = 0; i < 4; ++i)
            #pragma unroll
            for (int r = 0; r < 4; ++r) {
                int m = m0 + wr + i*16 + lhi*4 + r;
                out[(size_t)m * DIM + col] = acc[i][j][r] + bv;
            }
    }
}

extern "C" void kernel_launch(void* const* d_in, const int* in_sizes, int n_in,
                              void* d_out, int out_size, void* d_ws, size_t ws_size,
                              hipStream_t stream) {
    const float* x      = (const float*)d_in[0];
    const float* w_qkv  = (const float*)d_in[1];
    const float* b_qkv  = (const float*)d_in[2];
    const float* w_proj = (const float*)d_in[3];
    const float* b_proj = (const float*)d_in[4];
    float* out = (float*)d_out;

    const size_t NX  = (size_t)MTOT * DIM;
    const size_t NWQ = (size_t)3 * DIM * DIM;
    const size_t NWP = (size_t)DIM * DIM;
    const size_t NQ  = (size_t)BATCH * NHEAD * SEQ * HDIM;

    bf16_t* Xb    = (bf16_t*)d_ws;
    bf16_t* Wqkv  = Xb + NX;
    bf16_t* Wproj = Wqkv + NWQ;
    bf16_t* Qb    = Wproj + NWP;
    bf16_t* Kb    = Qb + NQ;
    bf16_t* Vtb   = Kb + NQ;
    bf16_t* AOb   = Vtb + NQ;

    cvt_kernel<<<(int)((NX + NWQ + NWP) / 1024), 256, 0, stream>>>(x, w_qkv, w_proj, Xb);

    gemm_qkv_kernel<<<768, 256, 0, stream>>>(Xb, Wqkv, b_qkv, Qb, Kb, Vtb);

    attn_kernel<<<256, 512, 0, stream>>>(Qb, Kb, Vtb, AOb);

    gemm_proj_kernel<<<512, 256, 0, stream>>>(AOb, Wproj, b_proj, out);
}